// Round 1
// baseline (71.254 us; speedup 1.0000x reference)
//
#include <hip/hip_runtime.h>

// ---- problem constants ----
#define B_NODES 4000
#define C_CH    128
#define E_ELEM  10
#define NT1 9
#define NT2 45
#define NT3 165
#define NT  219   // 9 + 45 + 165 monomials of degree 1..3 in 9 vars
#define DG  4     // output cols: (n0,d0), (n1,d0), (n1,d1), (n1,d2)

// irrep 0: d=1, k3=8, k2=3, k1=1 ; irrep 1: d=3, k3=11, k2=4, k1=1

// ---- workspace layout (floats for A, then bf16 G) ----
#define OFF_A3_0 0        // [165][8]
#define OFF_A3_1 1320     // [3][165][11]
#define OFF_A2_0 6765     // [45][3]
#define OFF_A2_1 6900     // [3][45][4]
#define OFF_A1_0 7440     // [9]
#define OFF_A1_1 7449     // [3][9]
#define A_TOTAL  7476
#define OFF_G_BYTES 32768 // G: ushort[E][NT][C][4]  (2,242,560 B)

__device__ inline void decode3(int t, int& i, int& j, int& p) {
    int idx = 0;
    for (int a = 0; a < 9; a++)
        for (int b = a; b < 9; b++)
            for (int c = b; c < 9; c++) {
                if (idx == t) { i = a; j = b; p = c; return; }
                idx++;
            }
}

__device__ inline void decode2(int t, int& i, int& j) {
    int idx = 0;
    for (int a = 0; a < 9; a++)
        for (int b = a; b < 9; b++) {
            if (idx == t) { i = a; j = b; return; }
            idx++;
        }
}

// sum of U3[d, perm(i,j,p), k] over distinct permutations (deterministic order)
__device__ inline float sum3(const float* U, int d, int K, int k, int i, int j, int p) {
    auto at = [&](int a, int b, int c) {
        return U[(((d * 9 + a) * 9 + b) * 9 + c) * K + k];
    };
    if (i == j && j == p) return at(i, i, i);
    if (i == j)           return at(i, i, p) + at(i, p, i) + at(p, i, i);
    if (j == p)           return at(i, j, j) + at(j, i, j) + at(j, j, i);
    return at(i, j, p) + at(i, p, j) + at(j, i, p) + at(j, p, i) + at(p, i, j) + at(p, j, i);
}

__device__ inline float sum2(const float* U, int d, int K, int k, int i, int j) {
    auto at = [&](int a, int b) { return U[((d * 9 + a) * 9 + b) * K + k]; };
    return (i == j) ? at(i, i) : (at(i, j) + at(j, i));
}

__device__ inline unsigned short f2bf(float f) { // RNE fp32 -> bf16
    unsigned u = __float_as_uint(f);
    unsigned r = u + 0x7fffu + ((u >> 16) & 1u);
    return (unsigned short)(r >> 16);
}

// ---- kernel 1: symmetrize U into A (deterministic, no atomics) ----
__global__ void a_build(const float* __restrict__ U3_0, const float* __restrict__ U2_0,
                        const float* __restrict__ U1_0, const float* __restrict__ U3_1,
                        const float* __restrict__ U2_1, const float* __restrict__ U1_1,
                        float* __restrict__ ws) {
    int tid = blockIdx.x * blockDim.x + threadIdx.x;
    if (tid < 1320) {                       // A3_0 [t3][k], d=0, K=8
        int t3 = tid / 8, k = tid % 8;
        int i, j, p; decode3(t3, i, j, p);
        ws[OFF_A3_0 + tid] = sum3(U3_0, 0, 8, k, i, j, p);
    } else if (tid < 1320 + 5445) {         // A3_1 [d][t3][k], K=11
        int r = tid - 1320;
        int d = r / (165 * 11); int r2 = r % (165 * 11);
        int t3 = r2 / 11, k = r2 % 11;
        int i, j, p; decode3(t3, i, j, p);
        ws[OFF_A3_1 + r] = sum3(U3_1, d, 11, k, i, j, p);
    } else if (tid < 6765 + 135) {          // A2_0 [t2][k], K=3
        int r = tid - 6765;
        int t2 = r / 3, k = r % 3;
        int i, j; decode2(t2, i, j);
        ws[OFF_A2_0 + r] = sum2(U2_0, 0, 3, k, i, j);
    } else if (tid < 6900 + 540) {          // A2_1 [d][t2][k], K=4
        int r = tid - 6900;
        int d = r / 180; int t2 = (r % 180) / 4; int k = r % 4;
        int i, j; decode2(t2, i, j);
        ws[OFF_A2_1 + r] = sum2(U2_1, d, 4, k, i, j);
    } else if (tid < 7440 + 9) {            // A1_0 [i]
        int i = tid - 7440;
        ws[OFF_A1_0 + i] = U1_0[i];
    } else if (tid < 7449 + 27) {           // A1_1 [d][i]
        int r = tid - 7449;
        ws[OFF_A1_1 + r] = U1_1[r];
    }
}

// ---- kernel 2: fuse weights into G[e][t][c][4] bf16 ----
__global__ void g_build(const float* __restrict__ W3_0, const float* __restrict__ W2_0,
                        const float* __restrict__ W1_0, const float* __restrict__ W3_1,
                        const float* __restrict__ W2_1, const float* __restrict__ W1_1,
                        const float* __restrict__ ws, unsigned short* __restrict__ G) {
    int tid = blockIdx.x * blockDim.x + threadIdx.x;
    if (tid >= E_ELEM * NT * C_CH) return;
    int c = tid & (C_CH - 1);
    int r = tid >> 7;          // r = e*NT + t
    int t = r % NT;
    int e = r / NT;

    float g[4];
    if (t < NT1) {
        int i = t;
        float w0 = W1_0[e * C_CH + c];
        float w1 = W1_1[e * C_CH + c];
        g[0] = ws[OFF_A1_0 + i] * w0;
        for (int d = 0; d < 3; d++) g[1 + d] = ws[OFF_A1_1 + d * 9 + i] * w1;
    } else if (t < NT1 + NT2) {
        int t2 = t - NT1;
        float s = 0.f;
        for (int k = 0; k < 3; k++) s += ws[OFF_A2_0 + t2 * 3 + k] * W2_0[(e * 3 + k) * C_CH + c];
        g[0] = s;
        for (int d = 0; d < 3; d++) {
            s = 0.f;
            for (int k = 0; k < 4; k++) s += ws[OFF_A2_1 + (d * 45 + t2) * 4 + k] * W2_1[(e * 4 + k) * C_CH + c];
            g[1 + d] = s;
        }
    } else {
        int t3 = t - NT1 - NT2;
        float s = 0.f;
        for (int k = 0; k < 8; k++) s += ws[OFF_A3_0 + t3 * 8 + k] * W3_0[(e * 8 + k) * C_CH + c];
        g[0] = s;
        for (int d = 0; d < 3; d++) {
            s = 0.f;
            for (int k = 0; k < 11; k++) s += ws[OFF_A3_1 + (d * 165 + t3) * 11 + k] * W3_1[(e * 11 + k) * C_CH + c];
            g[1 + d] = s;
        }
    }
    uint2 u;
    u.x = (unsigned)f2bf(g[0]) | ((unsigned)f2bf(g[1]) << 16);
    u.y = (unsigned)f2bf(g[2]) | ((unsigned)f2bf(g[3]) << 16);
    reinterpret_cast<uint2*>(G)[tid] = u;   // record index == tid by construction
}

// ---- kernel 3: main — per (b,c) thread: 219 monomials x 4 fused cols ----
__global__ void __launch_bounds__(C_CH) sc_main(const float* __restrict__ x,
                                                const float* __restrict__ attrs,
                                                const unsigned short* __restrict__ G,
                                                float* __restrict__ out) {
    int b = blockIdx.x;
    int c = threadIdx.x;

    // element index from one-hot attrs (uniform across block)
    int e = 0;
#pragma unroll
    for (int q = 0; q < E_ELEM; q++) e += (attrs[b * E_ELEM + q] > 0.5f) ? q : 0;

    float y[9];
#pragma unroll
    for (int i = 0; i < 9; i++) y[i] = x[(b * C_CH + c) * 9 + i];

    float d2[45];
    {
        int q = 0;
#pragma unroll
        for (int i = 0; i < 9; i++)
#pragma unroll
            for (int j = i; j < 9; j++) { d2[q] = y[i] * y[j]; q++; }
    }

    const uint2* gp = reinterpret_cast<const uint2*>(G) + (e * NT * C_CH + c);
    float a0 = 0.f, a1 = 0.f, a2 = 0.f, a3 = 0.f;

#define FMA4(U, PHI)                                                        \
    do {                                                                    \
        float _p = (PHI);                                                   \
        a0 = fmaf(_p, __uint_as_float((U).x << 16), a0);                    \
        a1 = fmaf(_p, __uint_as_float((U).x & 0xffff0000u), a1);            \
        a2 = fmaf(_p, __uint_as_float((U).y << 16), a2);                    \
        a3 = fmaf(_p, __uint_as_float((U).y & 0xffff0000u), a3);            \
    } while (0)

    int t = 0;
    // degree 1
#pragma unroll
    for (int i = 0; i < 9; i++) {
        uint2 u = gp[t * C_CH]; t++;
        FMA4(u, y[i]);
    }
    // degree 2
    {
        int q = 0;
#pragma unroll
        for (int i = 0; i < 9; i++)
#pragma unroll
            for (int j = i; j < 9; j++) {
                uint2 u = gp[t * C_CH]; t++;
                FMA4(u, d2[q]);
                q++;
            }
    }
    // degree 3
    {
        int q = 0;
#pragma unroll
        for (int i = 0; i < 9; i++)
#pragma unroll
            for (int j = i; j < 9; j++) {
#pragma unroll
                for (int p = j; p < 9; p++) {
                    uint2 u = gp[t * C_CH]; t++;
                    FMA4(u, d2[q] * y[p]);
                }
                q++;
            }
    }
#undef FMA4

    out[b * 512 + c] = a0;
    int o1 = b * 512 + 128 + 3 * c;
    out[o1 + 0] = a1;
    out[o1 + 1] = a2;
    out[o1 + 2] = a3;
}

extern "C" void kernel_launch(void* const* d_in, const int* in_sizes, int n_in,
                              void* d_out, int out_size, void* d_ws, size_t ws_size,
                              hipStream_t stream) {
    const float* x     = (const float*)d_in[0];
    const float* attrs = (const float*)d_in[1];
    const float* U3_0  = (const float*)d_in[2];
    const float* U2_0  = (const float*)d_in[3];
    const float* U1_0  = (const float*)d_in[4];
    const float* W3_0  = (const float*)d_in[5];
    const float* W2_0  = (const float*)d_in[6];
    const float* W1_0  = (const float*)d_in[7];
    const float* U3_1  = (const float*)d_in[8];
    const float* U2_1  = (const float*)d_in[9];
    const float* U1_1  = (const float*)d_in[10];
    const float* W3_1  = (const float*)d_in[11];
    const float* W2_1  = (const float*)d_in[12];
    const float* W1_1  = (const float*)d_in[13];

    float* wsA = (float*)d_ws;
    unsigned short* G = (unsigned short*)((char*)d_ws + OFF_G_BYTES);

    a_build<<<(A_TOTAL + 255) / 256, 256, 0, stream>>>(U3_0, U2_0, U1_0, U3_1, U2_1, U1_1, wsA);

    int ng = E_ELEM * NT * C_CH;
    g_build<<<(ng + 255) / 256, 256, 0, stream>>>(W3_0, W2_0, W1_0, W3_1, W2_1, W1_1, wsA, G);

    sc_main<<<B_NODES, C_CH, 0, stream>>>(x, attrs, G, (float*)d_out);
}

// Round 2
// 59.215 us; speedup vs baseline: 1.2033x; 1.2033x over previous
//
#include <hip/hip_runtime.h>
#include <utility>

typedef _Float16 f16x2 __attribute__((ext_vector_type(2)));

// ---- problem constants ----
#define B_NODES 4000
#define C_CH    128
#define E_ELEM  10
#define NT      219   // 9 + 45 + 165 monomials of degree 1..3 in 9 vars
#define NPAIR   110   // t-pairs (padded to 220)

// irrep 0: d=1, k3=8, k2=3, k1=1 ; irrep 1: d=3, k3=11, k2=4, k1=1

// ---- workspace layout (floats for A, then f16-packed G) ----
#define OFF_A3_0 0        // [165][8]
#define OFF_A3_1 1320     // [3][165][11]
#define OFF_A2_0 6765     // [45][3]
#define OFF_A2_1 6900     // [3][45][4]
#define OFF_A1_0 7440     // [9]
#define OFF_A1_1 7449     // [3][9]
#define A_TOTAL  7476
#define OFF_G_BYTES 32768 // G: uint4[E][NPAIR][C]  (2,252,800 B)

#if defined(__has_builtin)
#if __has_builtin(__builtin_amdgcn_fdot2)
#define HAVE_FDOT2 1
#endif
#endif

// ================= compile-time monomial table =================
struct M3 { int i, j, p, deg; };

constexpr M3 mono(int t) {
    if (t < 9) return M3{t, 0, 0, 1};
    int r = t - 9;
    if (r < 45) {
        int idx = 0;
        for (int a = 0; a < 9; a++)
            for (int b = a; b < 9; b++) {
                if (idx == r) return M3{a, b, 0, 2};
                idx++;
            }
    }
    r -= 45;
    {
        int idx = 0;
        for (int a = 0; a < 9; a++)
            for (int b = a; b < 9; b++)
                for (int c = b; c < 9; c++) {
                    if (idx == r) return M3{a, b, c, 3};
                    idx++;
                }
    }
    return M3{0, 0, 0, 0};
}

template <int T>
__device__ __forceinline__ float phi_t(const float (&y)[9]) {
    constexpr M3 m = mono(T);
    if constexpr (m.deg == 1) return y[m.i];
    else if constexpr (m.deg == 2) return y[m.i] * y[m.j];
    else return (y[m.i] * y[m.j]) * y[m.p];
}

// ================= helpers for precompute kernels =================
__device__ inline void decode3(int t, int& i, int& j, int& p) {
    int idx = 0;
    for (int a = 0; a < 9; a++)
        for (int b = a; b < 9; b++)
            for (int c = b; c < 9; c++) {
                if (idx == t) { i = a; j = b; p = c; return; }
                idx++;
            }
}

__device__ inline void decode2(int t, int& i, int& j) {
    int idx = 0;
    for (int a = 0; a < 9; a++)
        for (int b = a; b < 9; b++) {
            if (idx == t) { i = a; j = b; return; }
            idx++;
        }
}

__device__ inline float sum3(const float* U, int d, int K, int k, int i, int j, int p) {
    auto at = [&](int a, int b, int c) {
        return U[(((d * 9 + a) * 9 + b) * 9 + c) * K + k];
    };
    if (i == j && j == p) return at(i, i, i);
    if (i == j)           return at(i, i, p) + at(i, p, i) + at(p, i, i);
    if (j == p)           return at(i, j, j) + at(j, i, j) + at(j, j, i);
    return at(i, j, p) + at(i, p, j) + at(j, i, p) + at(j, p, i) + at(p, i, j) + at(p, j, i);
}

__device__ inline float sum2(const float* U, int d, int K, int k, int i, int j) {
    auto at = [&](int a, int b) { return U[((d * 9 + a) * 9 + b) * K + k]; };
    return (i == j) ? at(i, i) : (at(i, j) + at(j, i));
}

// ---- kernel 1: symmetrize U into A (deterministic, no atomics) ----
__global__ void a_build(const float* __restrict__ U3_0, const float* __restrict__ U2_0,
                        const float* __restrict__ U1_0, const float* __restrict__ U3_1,
                        const float* __restrict__ U2_1, const float* __restrict__ U1_1,
                        float* __restrict__ ws) {
    int tid = blockIdx.x * blockDim.x + threadIdx.x;
    if (tid < 1320) {                       // A3_0 [t3][k], d=0, K=8
        int t3 = tid / 8, k = tid % 8;
        int i, j, p; decode3(t3, i, j, p);
        ws[OFF_A3_0 + tid] = sum3(U3_0, 0, 8, k, i, j, p);
    } else if (tid < 1320 + 5445) {         // A3_1 [d][t3][k], K=11
        int r = tid - 1320;
        int d = r / (165 * 11); int r2 = r % (165 * 11);
        int t3 = r2 / 11, k = r2 % 11;
        int i, j, p; decode3(t3, i, j, p);
        ws[OFF_A3_1 + r] = sum3(U3_1, d, 11, k, i, j, p);
    } else if (tid < 6765 + 135) {          // A2_0 [t2][k], K=3
        int r = tid - 6765;
        int t2 = r / 3, k = r % 3;
        int i, j; decode2(t2, i, j);
        ws[OFF_A2_0 + r] = sum2(U2_0, 0, 3, k, i, j);
    } else if (tid < 6900 + 540) {          // A2_1 [d][t2][k], K=4
        int r = tid - 6900;
        int d = r / 180; int t2 = (r % 180) / 4; int k = r % 4;
        int i, j; decode2(t2, i, j);
        ws[OFF_A2_1 + r] = sum2(U2_1, d, 4, k, i, j);
    } else if (tid < 7440 + 9) {            // A1_0 [i]
        int i = tid - 7440;
        ws[OFF_A1_0 + i] = U1_0[i];
    } else if (tid < 7449 + 27) {           // A1_1 [d][i]
        int r = tid - 7449;
        ws[OFF_A1_1 + r] = U1_1[r];
    }
}

// ---- kernel 2: fuse weights into G[e][tp][c] = uint4 of 4x half2 ----
__device__ void compute_g(int t, int e, int c, const float* __restrict__ ws,
                          const float* __restrict__ W3_0, const float* __restrict__ W2_0,
                          const float* __restrict__ W1_0, const float* __restrict__ W3_1,
                          const float* __restrict__ W2_1, const float* __restrict__ W1_1,
                          float g[4]) {
    if (t >= NT) { g[0] = g[1] = g[2] = g[3] = 0.f; return; }
    if (t < 9) {
        int i = t;
        float w0 = W1_0[e * C_CH + c];
        float w1 = W1_1[e * C_CH + c];
        g[0] = ws[OFF_A1_0 + i] * w0;
        for (int d = 0; d < 3; d++) g[1 + d] = ws[OFF_A1_1 + d * 9 + i] * w1;
    } else if (t < 9 + 45) {
        int t2 = t - 9;
        float s = 0.f;
        for (int k = 0; k < 3; k++) s += ws[OFF_A2_0 + t2 * 3 + k] * W2_0[(e * 3 + k) * C_CH + c];
        g[0] = s;
        for (int d = 0; d < 3; d++) {
            s = 0.f;
            for (int k = 0; k < 4; k++) s += ws[OFF_A2_1 + (d * 45 + t2) * 4 + k] * W2_1[(e * 4 + k) * C_CH + c];
            g[1 + d] = s;
        }
    } else {
        int t3 = t - 54;
        float s = 0.f;
        for (int k = 0; k < 8; k++) s += ws[OFF_A3_0 + t3 * 8 + k] * W3_0[(e * 8 + k) * C_CH + c];
        g[0] = s;
        for (int d = 0; d < 3; d++) {
            s = 0.f;
            for (int k = 0; k < 11; k++) s += ws[OFF_A3_1 + (d * 165 + t3) * 11 + k] * W3_1[(e * 11 + k) * C_CH + c];
            g[1 + d] = s;
        }
    }
}

__device__ inline unsigned pack_h2(float a, float b) {
    unsigned short ha = __builtin_bit_cast(unsigned short, (_Float16)a);
    unsigned short hb = __builtin_bit_cast(unsigned short, (_Float16)b);
    return (unsigned)ha | ((unsigned)hb << 16);
}

__global__ void g_build(const float* __restrict__ W3_0, const float* __restrict__ W2_0,
                        const float* __restrict__ W1_0, const float* __restrict__ W3_1,
                        const float* __restrict__ W2_1, const float* __restrict__ W1_1,
                        const float* __restrict__ ws, uint4* __restrict__ G) {
    int tid = blockIdx.x * blockDim.x + threadIdx.x;
    if (tid >= E_ELEM * NPAIR * C_CH) return;
    int c = tid & (C_CH - 1);
    int r = tid >> 7;          // r = e*NPAIR + tp
    int tp = r % NPAIR;
    int e = r / NPAIR;

    float ga[4], gb[4];
    compute_g(2 * tp,     e, c, ws, W3_0, W2_0, W1_0, W3_1, W2_1, W1_1, ga);
    compute_g(2 * tp + 1, e, c, ws, W3_0, W2_0, W1_0, W3_1, W2_1, W1_1, gb);

    uint4 u;
    u.x = pack_h2(ga[0], gb[0]);
    u.y = pack_h2(ga[1], gb[1]);
    u.z = pack_h2(ga[2], gb[2]);
    u.w = pack_h2(ga[3], gb[3]);
    G[tid] = u;                // layout matches (e*NPAIR + tp)*C_CH + c
}

// ================= kernel 3: main =================
__device__ __forceinline__ float dot2acc(unsigned w, f16x2 p, float acc) {
#ifdef HAVE_FDOT2
    return __builtin_amdgcn_fdot2(__builtin_bit_cast(f16x2, w), p, acc, false);
#else
    f16x2 h = __builtin_bit_cast(f16x2, w);
    return fmaf((float)p.x, (float)h.x, fmaf((float)p.y, (float)h.y, acc));
#endif
}

template <int TP>
__device__ __forceinline__ void pair_step(const float (&y)[9], const uint4* __restrict__ gp,
                                          float& a0, float& a1, float& a2, float& a3) {
    uint4 u = gp[TP * C_CH];
    float p0 = phi_t<2 * TP>(y);
    float p1 = 0.f;
    if constexpr (2 * TP + 1 < NT) p1 = phi_t<2 * TP + 1>(y);
    f16x2 p;
    p.x = (_Float16)p0;
    p.y = (_Float16)p1;
    a0 = dot2acc(u.x, p, a0);
    a1 = dot2acc(u.y, p, a1);
    a2 = dot2acc(u.z, p, a2);
    a3 = dot2acc(u.w, p, a3);
}

template <std::size_t... I>
__device__ __forceinline__ void run_all(std::index_sequence<I...>, const float (&y)[9],
                                        const uint4* __restrict__ gp,
                                        float& a0, float& a1, float& a2, float& a3) {
    (pair_step<(int)I>(y, gp, a0, a1, a2, a3), ...);
}

__global__ void __launch_bounds__(C_CH, 8) sc_main(const float* __restrict__ x,
                                                   const float* __restrict__ attrs,
                                                   const uint4* __restrict__ G,
                                                   float* __restrict__ out) {
    __shared__ __align__(16) float xs[C_CH * 9];
    int b = blockIdx.x;
    int c = threadIdx.x;

    // stage x[b] (128x9 floats, 288 float4) coalesced into LDS
    const float4* xsrc = reinterpret_cast<const float4*>(x + (size_t)b * C_CH * 9);
    float4* xdst = reinterpret_cast<float4*>(xs);
#pragma unroll
    for (int k = 0; k < 3; k++) {
        int idx = c + k * C_CH;
        if (idx < 288) xdst[idx] = xsrc[idx];
    }

    // element index from one-hot attrs (block-uniform address -> scalarized)
    int e = 0;
#pragma unroll
    for (int q = 0; q < E_ELEM; q++) e += (attrs[b * E_ELEM + q] > 0.5f) ? q : 0;

    __syncthreads();

    float y[9];
#pragma unroll
    for (int i = 0; i < 9; i++) y[i] = xs[c * 9 + i];  // stride-9 dwords: conflict-free

    float a0 = 0.f, a1 = 0.f, a2 = 0.f, a3 = 0.f;
    const uint4* gp = G + ((size_t)e * NPAIR * C_CH + c);
    run_all(std::make_index_sequence<NPAIR>{}, y, gp, a0, a1, a2, a3);

    out[b * 512 + c] = a0;
    int o1 = b * 512 + 128 + 3 * c;
    out[o1 + 0] = a1;
    out[o1 + 1] = a2;
    out[o1 + 2] = a3;
}

extern "C" void kernel_launch(void* const* d_in, const int* in_sizes, int n_in,
                              void* d_out, int out_size, void* d_ws, size_t ws_size,
                              hipStream_t stream) {
    const float* x     = (const float*)d_in[0];
    const float* attrs = (const float*)d_in[1];
    const float* U3_0  = (const float*)d_in[2];
    const float* U2_0  = (const float*)d_in[3];
    const float* U1_0  = (const float*)d_in[4];
    const float* W3_0  = (const float*)d_in[5];
    const float* W2_0  = (const float*)d_in[6];
    const float* W1_0  = (const float*)d_in[7];
    const float* U3_1  = (const float*)d_in[8];
    const float* U2_1  = (const float*)d_in[9];
    const float* U1_1  = (const float*)d_in[10];
    const float* W3_1  = (const float*)d_in[11];
    const float* W2_1  = (const float*)d_in[12];
    const float* W1_1  = (const float*)d_in[13];

    float* wsA = (float*)d_ws;
    uint4* G = (uint4*)((char*)d_ws + OFF_G_BYTES);

    a_build<<<(A_TOTAL + 255) / 256, 256, 0, stream>>>(U3_0, U2_0, U1_0, U3_1, U2_1, U1_1, wsA);

    int ng = E_ELEM * NPAIR * C_CH;
    g_build<<<(ng + 255) / 256, 256, 0, stream>>>(W3_0, W2_0, W1_0, W3_1, W2_1, W1_1, wsA, G);

    sc_main<<<B_NODES, C_CH, 0, stream>>>(x, attrs, G, (float*)d_out);
}